// Round 1
// 337.514 us; speedup vs baseline: 1.0164x; 1.0164x over previous
//
#include <hip/hip_runtime.h>
#include <hip/hip_bf16.h>
#include <stdint.h>

#define NB 1024
#define NN 144
#define NH 4
#define HDIM 32
#define CC 384
#define SCALE_F 0.17677669529663687f

// LDS strides (bf16 elements). Multiples of 8 (16B) keep ds_read_b128 aligned;
// 40 and 168 give only 2-way bank aliasing (free per m136).
#define KSTR 40
#define VSTR 168
#define PSTR 168

typedef __attribute__((ext_vector_type(8))) short short8;
typedef __attribute__((ext_vector_type(4))) float float4v;

__device__ __forceinline__ uint16_t f2b(float f) {
    __hip_bfloat16 h = __float2bfloat16(f);
    return *reinterpret_cast<uint16_t*>(&h);
}

// One block per (b, h). 192 threads = 3 waves; each wave owns 3 query strips
// of 16 rows (9 strips = 144 rows). K and V^T staged once per block in LDS
// (fp32 -> bf16 during staging). Softmax is shuffle-free: no max subtraction
// (logits bounded ~|8|), row sums via an all-ones MFMA B-tile.
//
// Latency-hiding structure (this revision):
//  - staging issues ALL 12 global float4 loads before any convert/LDS-store
//    (one HBM latency exposure instead of six serialized ones)
//  - all 3 Q strips are prefetched (fp32 regs) before __syncthreads; the
//    barrier's vmcnt drain overlaps their completion with every wave's staging
//  - mask tile for strip s+1 is issued right after strip s's mask regs are
//    consumed (hidden under P-store + PV MFMAs + epilogue)
//
// XCD swizzle: round-robin dispatch maps blockIdx%8 -> XCD. We remap so the
// 4 heads of one batch b share blockIdx%8 (same XCD L2) and sit within 32
// dispatch slots of each other.
__global__ __launch_bounds__(192, 3) void attn_kernel(
    const float* __restrict__ qkv,   // fp32 [B][144][384]
    const float* __restrict__ mask,  // fp32 [4][144][144]
    float* __restrict__ out)         // fp32 [B][144][128]
{
    __shared__ __align__(16) uint16_t Kl[NN * KSTR];      // K  rows [ki][d]
    __shared__ __align__(16) uint16_t Vt[HDIM * VSTR];    // V^T rows [d][ki]
    __shared__ __align__(16) uint16_t Pb[3 * 16 * PSTR];  // per-wave P strip

    const int bid  = blockIdx.x;
    const int b    = ((bid >> 5) << 3) | (bid & 7);  // same-b heads share bid%8
    const int h    = (bid >> 3) & 3;
    const int tid  = threadIdx.x;
    const int wave = tid >> 6;
    const int lane = tid & 63;
    const int col  = lane & 15;   // A-frag m / B-frag n / C col
    const int quad = lane >> 4;   // k-chunk selector / C row group

    const float* qkv_b = qkv + (size_t)b * (NN * CC);
    const float* mbase = mask + h * (NN * NN);

    // ---- issue ALL staging loads first: 12 float4 in flight ----
    float4 kbuf[6], vbuf[6];
    #pragma unroll
    for (int i = 0; i < 6; i++) {
        const int idx = tid + i * 192;
        const int ki = idx >> 3;
        const int g  = idx & 7;
        kbuf[i] = *(const float4*)(qkv_b + ki * CC + 128 + h * HDIM + g * 4);
        vbuf[i] = *(const float4*)(qkv_b + ki * CC + 256 + h * HDIM + g * 4);
    }

    // ---- prefetch this wave's 3 Q strips (fp32; converted per strip) ----
    // A[m=col][k=quad*8+j] layout: row qi0+col, floats quad*8 .. quad*8+7.
    float4 qbuf[3][2];
    #pragma unroll
    for (int s3 = 0; s3 < 3; s3++) {
        const int qi0 = (wave + s3 * 3) * 16;
        const float* qp = qkv_b + (size_t)(qi0 + col) * CC + h * HDIM + quad * 8;
        qbuf[s3][0] = ((const float4*)qp)[0];
        qbuf[s3][1] = ((const float4*)qp)[1];
    }

    // ---- prefetch strip-0 mask tile (consumed in exp phase) ----
    float mreg[9][4];
    {
        const int qi0 = wave * 16;
        #pragma unroll
        for (int t = 0; t < 9; t++) {
            #pragma unroll
            for (int r = 0; r < 4; r++)
                mreg[t][r] = mbase[(qi0 + quad * 4 + r) * NN + t * 16 + col];
        }
    }

    // ---- convert + store staged K (row-major) and V (transposed) ----
    #pragma unroll
    for (int i = 0; i < 6; i++) {
        const int idx = tid + i * 192;
        const int ki = idx >> 3;
        const int g  = idx & 7;
        ushort4 kp;
        kp.x = f2b(kbuf[i].x); kp.y = f2b(kbuf[i].y);
        kp.z = f2b(kbuf[i].z); kp.w = f2b(kbuf[i].w);
        *(ushort4*)&Kl[ki * KSTR + g * 4] = kp;

        const int d0 = g * 4;
        Vt[(d0 + 0) * VSTR + ki] = f2b(vbuf[i].x);
        Vt[(d0 + 1) * VSTR + ki] = f2b(vbuf[i].y);
        Vt[(d0 + 2) * VSTR + ki] = f2b(vbuf[i].z);
        Vt[(d0 + 3) * VSTR + ki] = f2b(vbuf[i].w);
    }
    // zero Vt pad columns ki=144..159 (read by the last PV chunk)
    for (int i = tid; i < HDIM * 16; i += 192)
        Vt[(i >> 4) * VSTR + NN + (i & 15)] = 0;
    // zero own P-strip pad columns 144..159 (persist across strips; keeps the
    // ones-tile row sum exact over ki<144)
    uint16_t* Pw = &Pb[wave * 16 * PSTR];
    for (int i = lane; i < 16 * 16; i += 64)
        Pw[(i >> 4) * PSTR + NN + (i & 15)] = 0;

    __syncthreads();

    const float4v zf = {0.f, 0.f, 0.f, 0.f};

    // constant all-ones bf16 B-fragment (1.0 = 0x3F80) for row sums
    short8 ones;
    #pragma unroll
    for (int j = 0; j < 8; j++) ones[j] = (short)0x3F80;

    #pragma unroll
    for (int s3 = 0; s3 < 3; s3++) {
        const int qi0 = (wave + s3 * 3) * 16;

        // Q A-fragment: fp32 regs -> bf16 (VALU only, no memory)
        short8 qfrag;
        qfrag[0] = (short)f2b(qbuf[s3][0].x); qfrag[1] = (short)f2b(qbuf[s3][0].y);
        qfrag[2] = (short)f2b(qbuf[s3][0].z); qfrag[3] = (short)f2b(qbuf[s3][0].w);
        qfrag[4] = (short)f2b(qbuf[s3][1].x); qfrag[5] = (short)f2b(qbuf[s3][1].y);
        qfrag[6] = (short)f2b(qbuf[s3][1].z); qfrag[7] = (short)f2b(qbuf[s3][1].w);

        // ---- S = Q K^T : 9 ki-tiles, one 16x16x32 MFMA each ----
        float4v S[9];
        #pragma unroll
        for (int t = 0; t < 9; t++) {
            short8 kfrag = *(const short8*)&Kl[(t * 16 + col) * KSTR + quad * 8];
            S[t] = __builtin_amdgcn_mfma_f32_16x16x32_bf16(qfrag, kfrag, zf, 0, 0, 0);
        }

        // ---- P = exp(S*scale + mask), straight to LDS (no max, no shuffles) ----
        #pragma unroll
        for (int t = 0; t < 9; t++) {
            #pragma unroll
            for (int r = 0; r < 4; r++) {
                float p = __expf(fmaf(S[t][r], SCALE_F, mreg[t][r]));
                Pw[(quad * 4 + r) * PSTR + t * 16 + col] = f2b(p);
            }
        }

        // ---- prefetch next strip's mask (regs free now; latency hidden
        //      under the PV MFMAs + epilogue below) ----
        if (s3 < 2) {
            const int qn = (wave + (s3 + 1) * 3) * 16;
            #pragma unroll
            for (int t = 0; t < 9; t++) {
                #pragma unroll
                for (int r = 0; r < 4; r++)
                    mreg[t][r] = mbase[(qn + quad * 4 + r) * NN + t * 16 + col];
            }
        }

        // ---- O = P V (+ row sums L via ones-tile): 5 ki-chunks ----
        float4v O0 = zf, O1 = zf, L = zf;
        #pragma unroll
        for (int kt = 0; kt < 5; kt++) {
            short8 pfrag = *(const short8*)&Pw[col * PSTR + kt * 32 + quad * 8];
            short8 vf0   = *(const short8*)&Vt[col * VSTR + kt * 32 + quad * 8];
            short8 vf1   = *(const short8*)&Vt[(16 + col) * VSTR + kt * 32 + quad * 8];
            O0 = __builtin_amdgcn_mfma_f32_16x16x32_bf16(pfrag, vf0, O0, 0, 0, 0);
            O1 = __builtin_amdgcn_mfma_f32_16x16x32_bf16(pfrag, vf1, O1, 0, 0, 0);
            L  = __builtin_amdgcn_mfma_f32_16x16x32_bf16(pfrag, ones, L, 0, 0, 0);
        }

        // ---- epilogue: divide by row sum, store fp32 ----
        float* ob = out + ((size_t)b * NN + qi0) * 128 + h * HDIM;
        #pragma unroll
        for (int r = 0; r < 4; r++) {
            float inv = 1.0f / L[r];
            int orow = (quad * 4 + r) * 128;
            ob[orow + col]      = O0[r] * inv;
            ob[orow + 16 + col] = O1[r] * inv;
        }
    }
}

extern "C" void kernel_launch(void* const* d_in, const int* in_sizes, int n_in,
                              void* d_out, int out_size, void* d_ws, size_t ws_size,
                              hipStream_t stream) {
    const float* qkv  = (const float*)d_in[0];
    const float* mask = (const float*)d_in[1];
    float* out        = (float*)d_out;
    attn_kernel<<<dim3(NB * NH), dim3(192), 0, stream>>>(qkv, mask, out);
}